// Round 6
// baseline (109.893 us; speedup 1.0000x reference)
//
#include <hip/hip_runtime.h>

namespace {

constexpr float QSC = 0.18033688f;   // 0.125 * log2(e): fold 1/sqrt(d) and exp->exp2 into Q

typedef short bf16x8 __attribute__((ext_vector_type(8)));
typedef float f32x4 __attribute__((ext_vector_type(4)));

typedef __attribute__((address_space(3))) unsigned int lds_u32;
typedef __attribute__((address_space(1))) const unsigned int gbl_u32;

// hardware 2^x (v_exp_f32)
__device__ inline float exp2x(float x) { return __builtin_amdgcn_exp2f(x); }

// f32 -> bf16 round-to-nearest (half-up), packed pair (lo = a, hi = b) — cold paths
__device__ inline unsigned int pack2(float a, float b) {
  unsigned int ua = __builtin_bit_cast(unsigned int, a);
  unsigned int ub = __builtin_bit_cast(unsigned int, b);
  ua = (ua + 0x8000u) >> 16;
  ub = (ub + 0x8000u) & 0xFFFF0000u;
  return ua | ub;
}

// single-instruction packed f32->bf16 (hot loop): lo = bf16(a), hi = bf16(b)
__device__ inline unsigned int cvtpk(float a, float b) {
  unsigned int r;
  asm("v_cvt_pk_bf16_f32 %0, %1, %2" : "=v"(r) : "v"(a), "v"(b));
  return r;
}

// async global->LDS, 16B per lane; LDS dest = wave-uniform base + lane*16
__device__ inline void gl_lds16(const unsigned short* g, unsigned short* l) {
  __builtin_amdgcn_global_load_lds((gbl_u32*)g, (lds_u32*)l, 16, 0, 0);
}

__device__ inline bf16x8 ld16(const unsigned short* p) {
  uint4 u = *(const uint4*)p;
  return __builtin_bit_cast(bf16x8, u);
}

// v_permlane{32,16}_swap_b32: both operands are read-write.
__device__ inline void pswap32(unsigned int& a, unsigned int& b) {
  asm volatile("v_permlane32_swap_b32 %0, %1" : "+v"(a), "+v"(b));
}
__device__ inline void pswap16(unsigned int& a, unsigned int& b) {
  asm volatile("v_permlane16_swap_b32 %0, %1" : "+v"(a), "+v"(b));
}

// ---------------- pre-pass: K -> bf16 [b][key][d]; V -> bf16 transposed [b][d][key] ----------------
// XCD affinity: b = bid & 7 -> batch-b tiles produced on XCD b (warm L2 for fa).
__global__ __launch_bounds__(256) void prep(const float* __restrict__ K,
                                            const float* __restrict__ V,
                                            unsigned short* __restrict__ Kbf,
                                            unsigned short* __restrict__ Vtb) {
  __shared__ float Vl[64 * 65];
  const int bid = blockIdx.x;          // 512 = 8 batches (XCD) * 64 key tiles
  const int b = bid & 7, kt = bid >> 3;
  const int tid = threadIdx.x;
  const float4* Ks4 = (const float4*)(K + ((size_t)b * 4096 + kt * 64) * 64);
  const float4* Vs4 = (const float4*)(V + ((size_t)b * 4096 + kt * 64) * 64);
  #pragma unroll
  for (int i = 0; i < 4; ++i) {
    int idx = tid + 256 * i;
    int row = idx >> 4, c4 = idx & 15;
    float4 t = Ks4[idx];
    *(uint2*)&Kbf[((size_t)b * 4096 + kt * 64 + row) * 64 + c4 * 4] =
        make_uint2(pack2(t.x, t.y), pack2(t.z, t.w));
    float4 tv = Vs4[idx];
    float* d = &Vl[row * 65 + c4 * 4];
    d[0] = tv.x; d[1] = tv.y; d[2] = tv.z; d[3] = tv.w;
  }
  __syncthreads();
  #pragma unroll
  for (int i = 0; i < 4; ++i) {
    int idx = tid + 256 * i;
    int dd = idx >> 4, kc = idx & 15;
    float a  = Vl[(kc * 4 + 0) * 65 + dd];
    float b2 = Vl[(kc * 4 + 1) * 65 + dd];
    float c  = Vl[(kc * 4 + 2) * 65 + dd];
    float e  = Vl[(kc * 4 + 3) * 65 + dd];
    *(uint2*)&Vtb[((size_t)b * 64 + dd) * 4096 + kt * 64 + kc * 4] =
        make_uint2(pack2(a, b2), pack2(c, e));
  }
}

// ---------------- main: 256 threads = 4 waves = 2 key-halves x 2 q-halves ----------------
// NS = cross-BLOCK key-splits; split s handles kt ≡ s (mod NS); merge kernel
// (separate launch) normalizes. XCD BATCH AFFINITY (this revision): b = bid&7
// -> all blocks of batch b dispatch to XCD b (round-robin), shrinking the
// per-XCD L2 working set 64MB -> 8MB so the distance-1 prefetch hits local L2
// instead of L3/HBM. qt descending within each batch (longest first).
// Wave w -> (kh = w&1, qh = w>>1): S^T for K rows kh*32..+31 x Q rows
// qh*32..+31; half-K/half-V fragment reads; kh-pairs reduce O/l through LDS.
// LDS XOR-swizzled at 16B granularity; NO-MAX softmax (bounded logits -> exp2
// raw, deferred l); one raw barrier/iter, vmcnt(0) covers only loads issued a
// full iteration earlier (T3/T4); in-register P via permlane (T12); hot-loop
// bf16 pack via v_cvt_pk_bf16_f32; prefetch pointers strength-reduced.
// smem ushort map: K0 at 0 | K1 at 4096 | V0 at 8192 | V1 at 12288
template <int NS>
__launch_bounds__(256, 4)
__global__ void fa_mfma(const float* __restrict__ Q,
                        float* __restrict__ O,
                        const unsigned short* __restrict__ Kbf,
                        const unsigned short* __restrict__ Vtb,
                        float* __restrict__ Opart,   // (NS-1) partial slots in ws
                        float* __restrict__ lsum) {  // [NS][8*4096] row sums
  __shared__ __align__(16) unsigned short smem[16384];   // 32768 B

  const int bid = blockIdx.x;          // NS*512 blocks; XCD = batch = bid&7
  const int b  = bid & 7;
  const int rr = bid >> 3;             // 0..64*NS-1
  const int qt = 63 - rr / NS;
  const int s  = rr % NS;

  const int tid  = threadIdx.x;
  const int w    = tid >> 6;
  const int kh   = w & 1;        // key half
  const int qh   = w >> 1;       // q half
  const int lane = tid & 63;
  const int quad = lane >> 4;
  const int lc   = lane & 15;

  unsigned short* Kb0 = smem;
  unsigned short* Kb1 = smem + 4096;
  unsigned short* Vb0 = smem + 8192;
  unsigned short* Vb1 = smem + 12288;

  const unsigned short* Kt_g = Kbf + (size_t)b * 4096 * 64;   // [key][d]
  const unsigned short* Vt_g = Vtb + (size_t)b * 64 * 4096;   // [d][key]

  // staging geometry: wave w stages rows w*16..+15; lane -> row r0, phys chunk c0
  const int r0 = w * 16 + (lane >> 3);
  const int c0 = (lane & 7) ^ (r0 & 7);

  // fragment-read swizzled chunk offsets (ushorts): K chunk (4ks+quad)^(lc&7)
  const int ph0 = (quad ^ (lc & 7)) * 8;
  const int ph1 = ((4 + quad) ^ (lc & 7)) * 8;
  // V chunk (kh*4+quad)^(lc&7)
  const int phv = ((kh * 4 + quad) ^ (lc & 7)) * 8;

  const size_t tile_off = ((size_t)b * 4096 + (size_t)qt * 64) * 64;
  const float* Qb = Q + tile_off;

  // iterations this split owns: kt = NS*i + s, kt <= qt (0 possible when qt < s)
  const int nIter = (qt >= s) ? ((qt - s) / NS + 1) : 0;

  // ---- prologue: stage K(kt0), V(kt0) into buffer 0 (clamped if nIter==0) ----
  {
    const int kt0 = (s <= qt) ? s : qt;
    gl_lds16(Kt_g + (size_t)(kt0 * 64 + r0) * 64 + c0 * 8, Kb0 + w * 1024);
    gl_lds16(Kt_g + (size_t)(kt0 * 64 + r0 + 8) * 64 + c0 * 8, Kb0 + w * 1024 + 512);
    gl_lds16(Vt_g + (size_t)r0 * 4096 + kt0 * 64 + c0 * 8, Vb0 + w * 1024);
    gl_lds16(Vt_g + (size_t)(r0 + 8) * 4096 + kt0 * 64 + c0 * 8, Vb0 + w * 1024 + 512);
  }

  // strength-reduced prefetch pointers (iteration i prefetches kt = NS*(i+1)+s)
  const unsigned short* gk0 = Kt_g + (size_t)((NS + s) * 64 + r0) * 64 + c0 * 8;
  const unsigned short* gk1 = gk0 + (size_t)8 * 64;
  const unsigned short* gv0 = Vt_g + (size_t)r0 * 4096 + (NS + s) * 64 + c0 * 8;
  const unsigned short* gv1 = gv0 + (size_t)8 * 4096;
  constexpr size_t K_STEP = (size_t)NS * 64 * 64;   // ushorts per NS key tiles
  constexpr size_t V_STEP = (size_t)NS * 64;

  // ---- Q fragments for the wave's 32 rows (B-operand), scaled by 0.125*log2e ----
  bf16x8 qf[2][2];   // [tq][ks]; rows qh*32 + tq*16 + lc, dims ks*32 + quad*8
  #pragma unroll
  for (int tq = 0; tq < 2; ++tq) {
    const float* qrow = Qb + (qh * 32 + tq * 16 + lc) * 64 + quad * 8;
    #pragma unroll
    for (int ks = 0; ks < 2; ++ks) {
      float4 x = *(const float4*)(qrow + ks * 32);
      float4 y = *(const float4*)(qrow + ks * 32 + 4);
      uint4 u = make_uint4(pack2(x.x * QSC, x.y * QSC), pack2(x.z * QSC, x.w * QSC),
                           pack2(y.x * QSC, y.y * QSC), pack2(y.z * QSC, y.w * QSC));
      qf[tq][ks] = __builtin_bit_cast(bf16x8, u);
    }
  }

  float l4[2] = {0.0f, 0.0f};   // per-lane partial row-sums, one per q-subtile
  f32x4 o[2][4];                // o[tq][td]
  #pragma unroll
  for (int tq = 0; tq < 2; ++tq)
    #pragma unroll
    for (int td = 0; td < 4; ++td) o[tq][td] = f32x4{0.f, 0.f, 0.f, 0.f};

  // ---- shared iteration body ----
  auto body = [&](const unsigned short* Kcur, const unsigned short* Vcur, bool diag) __attribute__((always_inline)) {
    // S^T: K rows kh*32 + tk*16 + lc (A), Q cols (B); K-dim = 64
    bf16x8 kf[2][2];
    #pragma unroll
    for (int tk = 0; tk < 2; ++tk) {
      kf[tk][0] = ld16(&Kcur[(kh * 32 + tk * 16 + lc) * 64 + ph0]);
      kf[tk][1] = ld16(&Kcur[(kh * 32 + tk * 16 + lc) * 64 + ph1]);
    }
    f32x4 st[2][2];   // [tk][tq]
    __builtin_amdgcn_s_setprio(1);
    #pragma unroll
    for (int tk = 0; tk < 2; ++tk)
      #pragma unroll
      for (int tq = 0; tq < 2; ++tq) {
        f32x4 c = {0.f, 0.f, 0.f, 0.f};
        c = __builtin_amdgcn_mfma_f32_16x16x32_bf16(kf[tk][0], qf[tq][0], c, 0, 0, 0);
        c = __builtin_amdgcn_mfma_f32_16x16x32_bf16(kf[tk][1], qf[tq][1], c, 0, 0, 0);
        st[tk][tq] = c;
      }
    __builtin_amdgcn_s_setprio(0);

    // no-max softmax: P = exp2(s); accumulate l; pack bf16 via cvt_pk
    unsigned int pc[2][2][2];   // [tk][tq][half]
    #pragma unroll
    for (int tk = 0; tk < 2; ++tk)
      #pragma unroll
      for (int tq = 0; tq < 2; ++tq) {
        float e[4];
        #pragma unroll
        for (int r = 0; r < 4; ++r) {
          float v = st[tk][tq][r];
          if (diag) {
            int key_l = kh * 32 + tk * 16 + quad * 4 + r;
            int q_l   = qh * 32 + tq * 16 + lc;
            if (key_l > q_l) v = -1e30f;   // exp2 -> 0
          }
          e[r] = exp2x(v);
        }
        l4[tq] += (e[0] + e[1]) + (e[2] + e[3]);
        pc[tk][tq][0] = cvtpk(e[0], e[1]);
        pc[tk][tq][1] = cvtpk(e[2], e[3]);
      }

    // PV: A = P rows (permlane-built, K-dim = wave's 32 keys), B = V^T slice
    bf16x8 vf[4];
    #pragma unroll
    for (int td = 0; td < 4; ++td)
      vf[td] = ld16(&Vcur[(td * 16 + lc) * 64 + phv]);
    __builtin_amdgcn_s_setprio(1);
    #pragma unroll
    for (int tq = 0; tq < 2; ++tq) {
      unsigned int x0 = pc[0][tq][0], y0 = pc[1][tq][0];
      unsigned int x1 = pc[0][tq][1], y1 = pc[1][tq][1];
      pswap32(x0, y0); pswap16(x0, y0);
      pswap32(x1, y1); pswap16(x1, y1);
      bf16x8 a = __builtin_bit_cast(bf16x8, make_uint4(x0, x1, y0, y1));
      #pragma unroll
      for (int td = 0; td < 4; ++td)
        o[tq][td] = __builtin_amdgcn_mfma_f32_16x16x32_bf16(a, vf[td], o[tq][td], 0, 0, 0);
    }
    __builtin_amdgcn_s_setprio(0);
  };

  // ---- main loop: unmasked iterations with distance-1 prefetch ----
  for (int i = 0; i + 1 < nIter; ++i) {
    const unsigned short* Kcur = (i & 1) ? Kb1 : Kb0;
    const unsigned short* Vcur = (i & 1) ? Vb1 : Vb0;
    unsigned short* Knxt = (i & 1) ? Kb0 : Kb1;
    unsigned short* Vnxt = (i & 1) ? Vb0 : Vb1;

    // own prefetches from previous iteration have landed; barrier makes all waves'
    // staging visible AND retires every wave's reads of the buffer we overwrite next.
    asm volatile("s_waitcnt vmcnt(0)" ::: "memory");
    __builtin_amdgcn_s_barrier();

    // prefetch kt = NS*(i+1)+s (<= qt by construction)
    gl_lds16(gk0, Knxt + w * 1024);
    gl_lds16(gk1, Knxt + w * 1024 + 512);
    gl_lds16(gv0, Vnxt + w * 1024);
    gl_lds16(gv1, Vnxt + w * 1024 + 512);
    gk0 += K_STEP; gk1 += K_STEP; gv0 += V_STEP; gv1 += V_STEP;

    body(Kcur, Vcur, false);
  }

  // ---- final iteration: masked iff this split owns the diagonal tile ----
  if (nIter > 0) {
    const int il = nIter - 1;
    const unsigned short* Kcur = (il & 1) ? Kb1 : Kb0;
    const unsigned short* Vcur = (il & 1) ? Vb1 : Vb0;
    asm volatile("s_waitcnt vmcnt(0)" ::: "memory");
    __builtin_amdgcn_s_barrier();
    body(Kcur, Vcur, (NS * il + s) == qt);
  }

  // ---- drain everything (incl. unconsumed prologue stage when nIter==0),
  //      then reuse smem for the kh-pair O/l reduction ----
  __syncthreads();

  // cross-lane l reduce: sum the 4 quad replicas -> all lanes hold l[row=lc]
  #pragma unroll
  for (int tq = 0; tq < 2; ++tq) {
    l4[tq] += __shfl_xor(l4[tq], 16);
    l4[tq] += __shfl_xor(l4[tq], 32);
  }

  constexpr int MS = 66;
  float* buf  = (float*)smem;          // [64][MS] O partial from kh=1
  float* lbuf = buf + 64 * MS;         // [64] l partial from kh=1
  if (kh == 1) {
    #pragma unroll
    for (int tq = 0; tq < 2; ++tq) {
      #pragma unroll
      for (int r = 0; r < 4; ++r) {
        int row = qh * 32 + tq * 16 + quad * 4 + r;
        #pragma unroll
        for (int td = 0; td < 4; ++td)
          buf[row * MS + td * 16 + lc] = o[tq][td][r];
      }
      if (quad == 0) lbuf[qh * 32 + tq * 16 + lc] = l4[tq];
    }
  }
  __syncthreads();
  if (kh == 0) {
    #pragma unroll
    for (int tq = 0; tq < 2; ++tq) {
      l4[tq] += lbuf[qh * 32 + tq * 16 + lc];
      #pragma unroll
      for (int r = 0; r < 4; ++r) {
        int row = qh * 32 + tq * 16 + quad * 4 + r;
        #pragma unroll
        for (int td = 0; td < 4; ++td)
          o[tq][td][r] += buf[row * MS + td * 16 + lc];
      }
    }

    if constexpr (NS == 1) {
      float lv[2][4];
      #pragma unroll
      for (int tq = 0; tq < 2; ++tq) {
        float linv = 1.0f / l4[tq];
        #pragma unroll
        for (int r = 0; r < 4; ++r) lv[tq][r] = __shfl(linv, quad * 4 + r);
      }
      float* Ob = O + tile_off;
      #pragma unroll
      for (int tq = 0; tq < 2; ++tq)
        #pragma unroll
        for (int r = 0; r < 4; ++r) {
          int row = qh * 32 + tq * 16 + quad * 4 + r;
          #pragma unroll
          for (int td = 0; td < 4; ++td)
            Ob[row * 64 + td * 16 + lc] = o[tq][td][r] * lv[tq][r];
        }
    } else {
      // plain stores; the merge kernel (separate launch) is the synchronizer
      float* Oslot = (s == 0) ? (O + tile_off)
                              : (Opart + (size_t)(s - 1) * 2097152 + tile_off);
      #pragma unroll
      for (int tq = 0; tq < 2; ++tq) {
        #pragma unroll
        for (int r = 0; r < 4; ++r) {
          int row = qh * 32 + tq * 16 + quad * 4 + r;
          #pragma unroll
          for (int td = 0; td < 4; ++td)
            Oslot[row * 64 + td * 16 + lc] = o[tq][td][r];
        }
        if (quad == 0)
          lsum[s * 32768 + b * 4096 + qt * 64 + qh * 32 + tq * 16 + lc] = l4[tq];
      }
    }
  }
}

// ---------------- merge: O = (sum of NS partials) / (sum of NS row-sums) ----------------
// XCD affinity: block bid handles batch bid&7 -> reads fa's L2-resident partials.
template <int NS>
__global__ __launch_bounds__(256) void fa_merge(float* __restrict__ O,
                                               const float* __restrict__ Opart,
                                               const float* __restrict__ lsum) {
  const int b = blockIdx.x & 7;
  const int c = blockIdx.x >> 3;                       // 0..255 chunk within batch
  const int f = b * 262144 + c * 1024 + threadIdx.x * 4;   // f32 index
  const int row = f >> 6;
  float l = lsum[row];
  float4 acc = *(const float4*)&O[f];                  // split-0 partial lives in O
  #pragma unroll
  for (int s2 = 1; s2 < NS; ++s2) {
    l += lsum[s2 * 32768 + row];
    float4 p = *(const float4*)&Opart[(size_t)(s2 - 1) * 2097152 + f];
    acc.x += p.x; acc.y += p.y; acc.z += p.z; acc.w += p.w;
  }
  const float linv = 1.0f / l;
  acc.x *= linv; acc.y *= linv; acc.z *= linv; acc.w *= linv;
  *(float4*)&O[f] = acc;
}

}  // namespace

extern "C" void kernel_launch(void* const* d_in, const int* in_sizes, int n_in,
                              void* d_out, int out_size, void* d_ws, size_t ws_size,
                              hipStream_t stream) {
  const float* q = (const float*)d_in[0];
  const float* k = (const float*)d_in[1];
  const float* v = (const float*)d_in[2];
  float* out = (float*)d_out;

  unsigned short* Kbf = (unsigned short*)d_ws;                    // 4 MB
  unsigned short* Vtb = Kbf + (size_t)8 * 4096 * 64;              // 4 MB
  float* Opart = (float*)(Vtb + (size_t)8 * 4096 * 64);           // (NS-1) x 8 MB
  auto need = [&](int ns) {
    return (size_t)16 * 1024 * 1024 / 2 +                         // Kbf+Vtb = 8 MB
           (size_t)(ns - 1) * 2097152 * 4 +                       // partials
           (size_t)ns * 32768 * 4;                                // lsum
  };

  prep<<<dim3(512), dim3(256), 0, stream>>>(k, v, Kbf, Vtb);

  if (ws_size >= need(4)) {
    float* lsum = Opart + (size_t)3 * 2097152;
    fa_mfma<4><<<dim3(2048), dim3(256), 0, stream>>>(q, out, Kbf, Vtb, Opart, lsum);
    fa_merge<4><<<dim3(2048), dim3(256), 0, stream>>>(out, Opart, lsum);
  } else if (ws_size >= need(2)) {
    float* lsum = Opart + (size_t)1 * 2097152;
    fa_mfma<2><<<dim3(1024), dim3(256), 0, stream>>>(q, out, Kbf, Vtb, Opart, lsum);
    fa_merge<2><<<dim3(2048), dim3(256), 0, stream>>>(out, Opart, lsum);
  } else {
    fa_mfma<1><<<dim3(512), dim3(256), 0, stream>>>(q, out, Kbf, Vtb, nullptr, nullptr);
  }
}

// Round 7
// 108.161 us; speedup vs baseline: 1.0160x; 1.0160x over previous
//
#include <hip/hip_runtime.h>

namespace {

constexpr float QSC = 0.18033688f;   // 0.125 * log2(e): fold 1/sqrt(d) and exp->exp2 into Q

typedef short bf16x8 __attribute__((ext_vector_type(8)));
typedef float f32x4 __attribute__((ext_vector_type(4)));

// hardware 2^x (v_exp_f32)
__device__ inline float exp2x(float x) { return __builtin_amdgcn_exp2f(x); }

// f32 -> bf16 round-to-nearest (half-up), packed pair (lo = a, hi = b) — cold paths
__device__ inline unsigned int pack2(float a, float b) {
  unsigned int ua = __builtin_bit_cast(unsigned int, a);
  unsigned int ub = __builtin_bit_cast(unsigned int, b);
  ua = (ua + 0x8000u) >> 16;
  ub = (ub + 0x8000u) & 0xFFFF0000u;
  return ua | ub;
}

// single-instruction packed f32->bf16 (hot loop): lo = bf16(a), hi = bf16(b)
__device__ inline unsigned int cvtpk(float a, float b) {
  unsigned int r;
  asm("v_cvt_pk_bf16_f32 %0, %1, %2" : "=v"(r) : "v"(a), "v"(b));
  return r;
}

__device__ inline bf16x8 ld16(const unsigned short* p) {
  uint4 u = *(const uint4*)p;
  return __builtin_bit_cast(bf16x8, u);
}

// v_permlane{32,16}_swap_b32: both operands are read-write.
__device__ inline void pswap32(unsigned int& a, unsigned int& b) {
  asm volatile("v_permlane32_swap_b32 %0, %1" : "+v"(a), "+v"(b));
}
__device__ inline void pswap16(unsigned int& a, unsigned int& b) {
  asm volatile("v_permlane16_swap_b32 %0, %1" : "+v"(a), "+v"(b));
}

// ---------------- pre-pass: K -> bf16 [b][key][d]; V -> bf16 transposed [b][d][key] ----------------
// XCD affinity: b = bid & 7 -> batch-b tiles produced on XCD b (warm L2 for fa).
__global__ __launch_bounds__(256) void prep(const float* __restrict__ K,
                                            const float* __restrict__ V,
                                            unsigned short* __restrict__ Kbf,
                                            unsigned short* __restrict__ Vtb) {
  __shared__ float Vl[64 * 65];
  const int bid = blockIdx.x;          // 512 = 8 batches (XCD) * 64 key tiles
  const int b = bid & 7, kt = bid >> 3;
  const int tid = threadIdx.x;
  const float4* Ks4 = (const float4*)(K + ((size_t)b * 4096 + kt * 64) * 64);
  const float4* Vs4 = (const float4*)(V + ((size_t)b * 4096 + kt * 64) * 64);
  #pragma unroll
  for (int i = 0; i < 4; ++i) {
    int idx = tid + 256 * i;
    int row = idx >> 4, c4 = idx & 15;
    float4 t = Ks4[idx];
    *(uint2*)&Kbf[((size_t)b * 4096 + kt * 64 + row) * 64 + c4 * 4] =
        make_uint2(pack2(t.x, t.y), pack2(t.z, t.w));
    float4 tv = Vs4[idx];
    float* d = &Vl[row * 65 + c4 * 4];
    d[0] = tv.x; d[1] = tv.y; d[2] = tv.z; d[3] = tv.w;
  }
  __syncthreads();
  #pragma unroll
  for (int i = 0; i < 4; ++i) {
    int idx = tid + 256 * i;
    int dd = idx >> 4, kc = idx & 15;
    float a  = Vl[(kc * 4 + 0) * 65 + dd];
    float b2 = Vl[(kc * 4 + 1) * 65 + dd];
    float c  = Vl[(kc * 4 + 2) * 65 + dd];
    float e  = Vl[(kc * 4 + 3) * 65 + dd];
    *(uint2*)&Vtb[((size_t)b * 64 + dd) * 4096 + kt * 64 + kc * 4] =
        make_uint2(pack2(a, b2), pack2(c, e));
  }
}

// ---------------- main: 256 threads = 4 waves = 2 key-halves x 2 q-halves ----------------
// NS = cross-BLOCK key-splits; split s handles kt ≡ s (mod NS); merge kernel
// (separate launch) normalizes. XCD batch affinity: b = bid&7.
// ASYNC-STAGE SPLIT (this revision, T14): staging is global->REG loads issued a
// full iteration early, then ds_write_b128 to the next LDS buffer AFTER the
// body; the per-iteration barrier is raw s_barrier preceded by lgkmcnt(0) ONLY.
// No vmcnt drain anywhere in the loop — the compiler's counted vmcnt lands
// before the ds_write (first register use), hidden under body + barrier. This
// removes the global_load_lds DMA-completion latency from the 4-wave
// rendezvous, which the r2/r4 scaling data identified as the ~4800-cyc
// per-iteration critical path.
// Wave w -> (kh = w&1, qh = w>>1); half-K/half-V fragment reads; kh-pairs
// reduce O/l through LDS in the epilogue. LDS XOR-swizzled at 16B granularity;
// NO-MAX softmax; in-register P via permlane (T12); cvt_pk bf16 pack.
// smem ushort map: K0 at 0 | K1 at 4096 | V0 at 8192 | V1 at 12288
template <int NS>
__launch_bounds__(256, 4)
__global__ void fa_mfma(const float* __restrict__ Q,
                        float* __restrict__ O,
                        const unsigned short* __restrict__ Kbf,
                        const unsigned short* __restrict__ Vtb,
                        float* __restrict__ Opart,   // (NS-1) partial slots in ws
                        float* __restrict__ lsum) {  // [NS][8*4096] row sums
  __shared__ __align__(16) unsigned short smem[16384];   // 32768 B

  const int bid = blockIdx.x;          // NS*512 blocks; XCD = batch = bid&7
  const int b  = bid & 7;
  const int rr = bid >> 3;             // 0..64*NS-1
  const int qt = 63 - rr / NS;
  const int s  = rr % NS;

  const int tid  = threadIdx.x;
  const int w    = tid >> 6;
  const int kh   = w & 1;        // key half
  const int qh   = w >> 1;       // q half
  const int lane = tid & 63;
  const int quad = lane >> 4;
  const int lc   = lane & 15;

  unsigned short* Kb0 = smem;
  unsigned short* Kb1 = smem + 4096;
  unsigned short* Vb0 = smem + 8192;
  unsigned short* Vb1 = smem + 12288;

  const unsigned short* Kt_g = Kbf + (size_t)b * 4096 * 64;   // [key][d]
  const unsigned short* Vt_g = Vtb + (size_t)b * 64 * 4096;   // [d][key]

  // staging geometry: wave w stages rows w*16..+15; lane -> row r0, phys chunk c0
  const int r0 = w * 16 + (lane >> 3);
  const int c0 = (lane & 7) ^ (r0 & 7);
  const size_t koff = (size_t)r0 * 64 + (size_t)c0 * 8;     // + kt*4096
  const size_t voff = (size_t)r0 * 4096 + (size_t)c0 * 8;   // + kt*64
  const int lw0 = w * 1024 + lane * 8;                      // LDS ushort idx, lane's 16B
  const int lw1 = lw0 + 512;

  // fragment-read swizzled chunk offsets (ushorts): K chunk (4ks+quad)^(lc&7)
  const int ph0 = (quad ^ (lc & 7)) * 8;
  const int ph1 = ((4 + quad) ^ (lc & 7)) * 8;
  // V chunk (kh*4+quad)^(lc&7)
  const int phv = ((kh * 4 + quad) ^ (lc & 7)) * 8;

  const size_t tile_off = ((size_t)b * 4096 + (size_t)qt * 64) * 64;
  const float* Qb = Q + tile_off;

  // iterations this split owns: kt = NS*i + s, kt <= qt (0 possible when qt < s)
  const int nIter = (qt >= s) ? ((qt - s) / NS + 1) : 0;

  // ---- prologue: issue tile-0 staging loads into registers ----
  uint4 sK0 = {}, sK1 = {}, sV0 = {}, sV1 = {};
  if (nIter > 0) {
    const unsigned short* gkp = Kt_g + (size_t)s * 4096 + koff;
    sK0 = *(const uint4*)gkp;
    sK1 = *(const uint4*)(gkp + 8 * 64);
    const unsigned short* gvp = Vt_g + (size_t)s * 64 + voff;
    sV0 = *(const uint4*)gvp;
    sV1 = *(const uint4*)(gvp + 8 * 4096);
  }

  // ---- Q fragments (B-operand), scaled by 0.125*log2e (hides staging latency) ----
  bf16x8 qf[2][2];   // [tq][ks]; rows qh*32 + tq*16 + lc, dims ks*32 + quad*8
  #pragma unroll
  for (int tq = 0; tq < 2; ++tq) {
    const float* qrow = Qb + (qh * 32 + tq * 16 + lc) * 64 + quad * 8;
    #pragma unroll
    for (int ks = 0; ks < 2; ++ks) {
      float4 x = *(const float4*)(qrow + ks * 32);
      float4 y = *(const float4*)(qrow + ks * 32 + 4);
      uint4 u = make_uint4(pack2(x.x * QSC, x.y * QSC), pack2(x.z * QSC, x.w * QSC),
                           pack2(y.x * QSC, y.y * QSC), pack2(y.z * QSC, y.w * QSC));
      qf[tq][ks] = __builtin_bit_cast(bf16x8, u);
    }
  }

  // ---- prologue: write tile 0 to buffer 0; issue tile-1 loads ----
  if (nIter > 0) {
    *(uint4*)&Kb0[lw0] = sK0;
    *(uint4*)&Kb0[lw1] = sK1;
    *(uint4*)&Vb0[lw0] = sV0;
    *(uint4*)&Vb0[lw1] = sV1;
    if (nIter > 1) {
      const int kt1 = NS + s;
      const unsigned short* gkp = Kt_g + (size_t)kt1 * 4096 + koff;
      sK0 = *(const uint4*)gkp;
      sK1 = *(const uint4*)(gkp + 8 * 64);
      const unsigned short* gvp = Vt_g + (size_t)kt1 * 64 + voff;
      sV0 = *(const uint4*)gvp;
      sV1 = *(const uint4*)(gvp + 8 * 4096);
    }
  }

  float l4[2] = {0.0f, 0.0f};   // per-lane partial row-sums, one per q-subtile
  f32x4 o[2][4];                // o[tq][td]
  #pragma unroll
  for (int tq = 0; tq < 2; ++tq)
    #pragma unroll
    for (int td = 0; td < 4; ++td) o[tq][td] = f32x4{0.f, 0.f, 0.f, 0.f};

  // ---- shared iteration body ----
  auto body = [&](const unsigned short* Kcur, const unsigned short* Vcur, bool diag) __attribute__((always_inline)) {
    // S^T: K rows kh*32 + tk*16 + lc (A), Q cols (B); K-dim = 64
    bf16x8 kf[2][2];
    #pragma unroll
    for (int tk = 0; tk < 2; ++tk) {
      kf[tk][0] = ld16(&Kcur[(kh * 32 + tk * 16 + lc) * 64 + ph0]);
      kf[tk][1] = ld16(&Kcur[(kh * 32 + tk * 16 + lc) * 64 + ph1]);
    }
    f32x4 st[2][2];   // [tk][tq]
    __builtin_amdgcn_s_setprio(1);
    #pragma unroll
    for (int tk = 0; tk < 2; ++tk)
      #pragma unroll
      for (int tq = 0; tq < 2; ++tq) {
        f32x4 c = {0.f, 0.f, 0.f, 0.f};
        c = __builtin_amdgcn_mfma_f32_16x16x32_bf16(kf[tk][0], qf[tq][0], c, 0, 0, 0);
        c = __builtin_amdgcn_mfma_f32_16x16x32_bf16(kf[tk][1], qf[tq][1], c, 0, 0, 0);
        st[tk][tq] = c;
      }
    __builtin_amdgcn_s_setprio(0);

    // no-max softmax: P = exp2(s); accumulate l; pack bf16 via cvt_pk
    unsigned int pc[2][2][2];   // [tk][tq][half]
    #pragma unroll
    for (int tk = 0; tk < 2; ++tk)
      #pragma unroll
      for (int tq = 0; tq < 2; ++tq) {
        float e[4];
        #pragma unroll
        for (int r = 0; r < 4; ++r) {
          float v = st[tk][tq][r];
          if (diag) {
            int key_l = kh * 32 + tk * 16 + quad * 4 + r;
            int q_l   = qh * 32 + tq * 16 + lc;
            if (key_l > q_l) v = -1e30f;   // exp2 -> 0
          }
          e[r] = exp2x(v);
        }
        l4[tq] += (e[0] + e[1]) + (e[2] + e[3]);
        pc[tk][tq][0] = cvtpk(e[0], e[1]);
        pc[tk][tq][1] = cvtpk(e[2], e[3]);
      }

    // PV: A = P rows (permlane-built, K-dim = wave's 32 keys), B = V^T slice
    bf16x8 vf[4];
    #pragma unroll
    for (int td = 0; td < 4; ++td)
      vf[td] = ld16(&Vcur[(td * 16 + lc) * 64 + phv]);
    __builtin_amdgcn_s_setprio(1);
    #pragma unroll
    for (int tq = 0; tq < 2; ++tq) {
      unsigned int x0 = pc[0][tq][0], y0 = pc[1][tq][0];
      unsigned int x1 = pc[0][tq][1], y1 = pc[1][tq][1];
      pswap32(x0, y0); pswap16(x0, y0);
      pswap32(x1, y1); pswap16(x1, y1);
      bf16x8 a = __builtin_bit_cast(bf16x8, make_uint4(x0, x1, y0, y1));
      #pragma unroll
      for (int td = 0; td < 4; ++td)
        o[tq][td] = __builtin_amdgcn_mfma_f32_16x16x32_bf16(a, vf[td], o[tq][td], 0, 0, 0);
    }
    __builtin_amdgcn_s_setprio(0);
  };

  // ---- main loop: body(i) | ds_write tile i+1 | issue loads tile i+2 ----
  for (int i = 0; i + 1 < nIter; ++i) {
    const unsigned short* Kcur = (i & 1) ? Kb1 : Kb0;
    const unsigned short* Vcur = (i & 1) ? Vb1 : Vb0;
    unsigned short* Knxt = (i & 1) ? Kb0 : Kb1;
    unsigned short* Vnxt = (i & 1) ? Vb0 : Vb1;

    // raw barrier: LDS writes of tile i visible; buffer (i+1) free for rewrite.
    // lgkmcnt(0) only — staging loads (vmcnt) stay in flight across the barrier.
    asm volatile("s_waitcnt lgkmcnt(0)" ::: "memory");
    __builtin_amdgcn_s_barrier();

    body(Kcur, Vcur, false);

    // write tile i+1 (regs loaded a full iteration ago; compiler-counted vmcnt)
    *(uint4*)&Knxt[lw0] = sK0;
    *(uint4*)&Knxt[lw1] = sK1;
    *(uint4*)&Vnxt[lw0] = sV0;
    *(uint4*)&Vnxt[lw1] = sV1;

    if (i + 2 < nIter) {   // issue tile i+2 staging loads (uniform branch)
      const int ktn = NS * (i + 2) + s;
      const unsigned short* gkp = Kt_g + (size_t)ktn * 4096 + koff;
      sK0 = *(const uint4*)gkp;
      sK1 = *(const uint4*)(gkp + 8 * 64);
      const unsigned short* gvp = Vt_g + (size_t)ktn * 64 + voff;
      sV0 = *(const uint4*)gvp;
      sV1 = *(const uint4*)(gvp + 8 * 4096);
    }
  }

  // ---- final iteration: masked iff this split owns the diagonal tile ----
  if (nIter > 0) {
    const int il = nIter - 1;
    const unsigned short* Kcur = (il & 1) ? Kb1 : Kb0;
    const unsigned short* Vcur = (il & 1) ? Vb1 : Vb0;
    asm volatile("s_waitcnt lgkmcnt(0)" ::: "memory");
    __builtin_amdgcn_s_barrier();
    body(Kcur, Vcur, (NS * il + s) == qt);
  }

  // ---- full drain, then reuse smem for the kh-pair O/l reduction ----
  __syncthreads();

  // cross-lane l reduce: sum the 4 quad replicas -> all lanes hold l[row=lc]
  #pragma unroll
  for (int tq = 0; tq < 2; ++tq) {
    l4[tq] += __shfl_xor(l4[tq], 16);
    l4[tq] += __shfl_xor(l4[tq], 32);
  }

  constexpr int MS = 66;
  float* buf  = (float*)smem;          // [64][MS] O partial from kh=1
  float* lbuf = buf + 64 * MS;         // [64] l partial from kh=1
  if (kh == 1) {
    #pragma unroll
    for (int tq = 0; tq < 2; ++tq) {
      #pragma unroll
      for (int r = 0; r < 4; ++r) {
        int row = qh * 32 + tq * 16 + quad * 4 + r;
        #pragma unroll
        for (int td = 0; td < 4; ++td)
          buf[row * MS + td * 16 + lc] = o[tq][td][r];
      }
      if (quad == 0) lbuf[qh * 32 + tq * 16 + lc] = l4[tq];
    }
  }
  __syncthreads();
  if (kh == 0) {
    #pragma unroll
    for (int tq = 0; tq < 2; ++tq) {
      l4[tq] += lbuf[qh * 32 + tq * 16 + lc];
      #pragma unroll
      for (int r = 0; r < 4; ++r) {
        int row = qh * 32 + tq * 16 + quad * 4 + r;
        #pragma unroll
        for (int td = 0; td < 4; ++td)
          o[tq][td][r] += buf[row * MS + td * 16 + lc];
      }
    }

    if constexpr (NS == 1) {
      float lv[2][4];
      #pragma unroll
      for (int tq = 0; tq < 2; ++tq) {
        float linv = 1.0f / l4[tq];
        #pragma unroll
        for (int r = 0; r < 4; ++r) lv[tq][r] = __shfl(linv, quad * 4 + r);
      }
      float* Ob = O + tile_off;
      #pragma unroll
      for (int tq = 0; tq < 2; ++tq)
        #pragma unroll
        for (int r = 0; r < 4; ++r) {
          int row = qh * 32 + tq * 16 + quad * 4 + r;
          #pragma unroll
          for (int td = 0; td < 4; ++td)
            Ob[row * 64 + td * 16 + lc] = o[tq][td][r] * lv[tq][r];
        }
    } else {
      // plain stores; the merge kernel (separate launch) is the synchronizer
      float* Oslot = (s == 0) ? (O + tile_off)
                              : (Opart + (size_t)(s - 1) * 2097152 + tile_off);
      #pragma unroll
      for (int tq = 0; tq < 2; ++tq) {
        #pragma unroll
        for (int r = 0; r < 4; ++r) {
          int row = qh * 32 + tq * 16 + quad * 4 + r;
          #pragma unroll
          for (int td = 0; td < 4; ++td)
            Oslot[row * 64 + td * 16 + lc] = o[tq][td][r];
        }
        if (quad == 0)
          lsum[s * 32768 + b * 4096 + qt * 64 + qh * 32 + tq * 16 + lc] = l4[tq];
      }
    }
  }
}

// ---------------- merge: O = (sum of NS partials) / (sum of NS row-sums) ----------------
// XCD affinity: block bid handles batch bid&7 -> reads fa's L2-resident partials.
template <int NS>
__global__ __launch_bounds__(256) void fa_merge(float* __restrict__ O,
                                               const float* __restrict__ Opart,
                                               const float* __restrict__ lsum) {
  const int b = blockIdx.x & 7;
  const int c = blockIdx.x >> 3;                       // 0..255 chunk within batch
  const int f = b * 262144 + c * 1024 + threadIdx.x * 4;   // f32 index
  const int row = f >> 6;
  float l = lsum[row];
  float4 acc = *(const float4*)&O[f];                  // split-0 partial lives in O
  #pragma unroll
  for (int s2 = 1; s2 < NS; ++s2) {
    l += lsum[s2 * 32768 + row];
    float4 p = *(const float4*)&Opart[(size_t)(s2 - 1) * 2097152 + f];
    acc.x += p.x; acc.y += p.y; acc.z += p.z; acc.w += p.w;
  }
  const float linv = 1.0f / l;
  acc.x *= linv; acc.y *= linv; acc.z *= linv; acc.w *= linv;
  *(float4*)&O[f] = acc;
}

}  // namespace

extern "C" void kernel_launch(void* const* d_in, const int* in_sizes, int n_in,
                              void* d_out, int out_size, void* d_ws, size_t ws_size,
                              hipStream_t stream) {
  const float* q = (const float*)d_in[0];
  const float* k = (const float*)d_in[1];
  const float* v = (const float*)d_in[2];
  float* out = (float*)d_out;

  unsigned short* Kbf = (unsigned short*)d_ws;                    // 4 MB
  unsigned short* Vtb = Kbf + (size_t)8 * 4096 * 64;              // 4 MB
  float* Opart = (float*)(Vtb + (size_t)8 * 4096 * 64);           // (NS-1) x 8 MB
  auto need = [&](int ns) {
    return (size_t)16 * 1024 * 1024 / 2 +                         // Kbf+Vtb = 8 MB
           (size_t)(ns - 1) * 2097152 * 4 +                       // partials
           (size_t)ns * 32768 * 4;                                // lsum
  };

  prep<<<dim3(512), dim3(256), 0, stream>>>(k, v, Kbf, Vtb);

  if (ws_size >= need(4)) {
    float* lsum = Opart + (size_t)3 * 2097152;
    fa_mfma<4><<<dim3(2048), dim3(256), 0, stream>>>(q, out, Kbf, Vtb, Opart, lsum);
    fa_merge<4><<<dim3(2048), dim3(256), 0, stream>>>(out, Opart, lsum);
  } else if (ws_size >= need(2)) {
    float* lsum = Opart + (size_t)1 * 2097152;
    fa_mfma<2><<<dim3(1024), dim3(256), 0, stream>>>(q, out, Kbf, Vtb, Opart, lsum);
    fa_merge<2><<<dim3(2048), dim3(256), 0, stream>>>(out, Opart, lsum);
  } else {
    fa_mfma<1><<<dim3(512), dim3(256), 0, stream>>>(q, out, Kbf, Vtb, nullptr, nullptr);
  }
}